// Round 2
// baseline (275.368 us; speedup 1.0000x reference)
//
#include <hip/hip_runtime.h>
#include <stdint.h>

#define NPTS 32768
#define KOFF 27
#define CH   128
#define NC   (NPTS*CH)
#define TILE_M 128
#define NITER (KOFF*2)     // 54 BK=64 steps per block (h outer, kk inner)

typedef __attribute__((ext_vector_type(8))) short short8;   // 8 bf16 (MFMA A/B frag)
typedef __attribute__((ext_vector_type(4))) float f32x4;    // MFMA C/D frag
typedef unsigned short u16;

__device__ __forceinline__ float bf2f(u16 u) {
    union { uint32_t i; float f; } v; v.i = ((uint32_t)u) << 16; return v.f;
}
__device__ __forceinline__ u16 f2bf(float f) {
    union { float f; uint32_t i; } v; v.f = f;
    return (u16)((v.i + 0x7FFF + ((v.i >> 16) & 1)) >> 16);  // RNE
}

#define GLDS16(gp, lp) __builtin_amdgcn_global_load_lds( \
    (__attribute__((address_space(1))) void*)(gp),           \
    (__attribute__((address_space(3))) void*)(lp), 16, 0, 0)

// ---------------------------------------------------------------------------
// prep (fused): b<54 -> W[k][c][d] fp32 -> Wt[k][d][c] bf16; block 0 zeros
// stats; b>=54 -> feats fp32 -> bf16 (8 elems/thread)
// ---------------------------------------------------------------------------
__global__ __launch_bounds__(256)
void prep_kernel(const float* __restrict__ W1, const float* __restrict__ W2,
                 u16* __restrict__ W1t, u16* __restrict__ W2t,
                 const float* __restrict__ feats, u16* __restrict__ xbuf,
                 float* __restrict__ stat)
{
    __shared__ u16 t[128*129];
    const int b = blockIdx.x, tid = threadIdx.x;
    if (b < 2*KOFF) {
        if (b == 0) for (int i = tid; i < 512; i += 256) stat[i] = 0.0f;
        const float* src = (b < KOFF) ? W1 + (size_t)b*CH*CH : W2 + (size_t)(b-KOFF)*CH*CH;
        u16* dst         = (b < KOFF) ? W1t + (size_t)b*CH*CH : W2t + (size_t)(b-KOFF)*CH*CH;
        for (int e = tid; e < CH*CH; e += 256) {
            int c = e >> 7, d = e & 127;
            t[d*129 + c] = f2bf(src[e]);
        }
        __syncthreads();
        for (int e = tid; e < CH*CH; e += 256) {
            int d = e >> 7, c = e & 127;
            dst[e] = t[d*129 + c];
        }
    } else {
        size_t e = ((size_t)(b - 2*KOFF) * 256 + tid) * 8;
        float4 a = *(const float4*)(feats + e);
        float4 c = *(const float4*)(feats + e + 4);
        ushort4 lo, hi;
        lo.x = f2bf(a.x); lo.y = f2bf(a.y); lo.z = f2bf(a.z); lo.w = f2bf(a.w);
        hi.x = f2bf(c.x); hi.y = f2bf(c.y); hi.z = f2bf(c.z); hi.w = f2bf(c.w);
        *(ushort4*)(xbuf + e) = lo;
        *(ushort4*)(xbuf + e + 4) = hi;
    }
}

// ---------------------------------------------------------------------------
// gathered MFMA GEMM, full-K per block + fused BN stats.
// NEW (this round): KSPLIT=1 -- grid 256 blocks (1/CU), each block does all
// 27 k-offsets (54 BK=64 steps) for its 128 rows. The partials pipeline
// (3x8.4 MB write + 25.2 MB sumstats re-read + 2 launches) disappears:
// epilogue holds the full fp32 K-sum, writes y bf16 (8.4 MB) and does exact
// per-channel sum/sumsq via LDS + 128 global atomics per block.
// At 1 block/CU the staging drain has no co-resident blocks to hide it, so
// the K-loop is 2-phase double-buffered (T3-lite): STAGE(next) issued BEFORE
// compute(cur), one __syncthreads per step -- staging latency overlaps the
// MFMA phase. LDS 79.6 KB (2x16 A + 2x16 B dbuf + 13.8 idx + 1 stats).
// 128x128 tile, 4 waves each 64x64 (acc[4][4]), 16x16x32 bf16 MFMA, BK=64,
// GLDS16 with source-chunk XOR swizzle. h (row half) OUTER: halves the
// instantaneous gather working set (8.4 -> 4.2 MB ~ per-XCD L2).
// ---------------------------------------------------------------------------
__global__ __launch_bounds__(256, 1)
void ResidualBlock_77498389889548_kernel(const u16* __restrict__ xb,
                                         const int* __restrict__ nbr,
                                         const u16* __restrict__ Wt,
                                         u16* __restrict__ y,
                                         float* __restrict__ gsum,
                                         float* __restrict__ gsq)
{
    __shared__ __align__(16) u16 A_lds[2][TILE_M*64];   // 2 x 16 KB swizzled
    __shared__ __align__(16) u16 B_lds[2][CH*64];       // 2 x 16 KB swizzled
    __shared__ int idx_lds[KOFF*TILE_M];                // 13.8 KB, [r][kk]
    __shared__ float ls[CH], lq[CH];

    const int tid = threadIdx.x;
    const int n0  = blockIdx.x * TILE_M;

    // coalesced idx load: nbr rows n0..n0+127 are KOFF*TILE_M consecutive ints
    const int* nbl = nbr + (size_t)n0 * KOFF;
    for (int e = tid; e < KOFF*TILE_M; e += 256) {
        int v = nbl[e];
        idx_lds[e] = ((unsigned)v < (unsigned)NPTS) ? v : 0;   // [r*27 + kk]
    }
    if (tid < CH) { ls[tid] = 0.0f; lq[tid] = 0.0f; }
    __syncthreads();

    const int wave = tid >> 6;
    const int lane = tid & 63;
    const int wrow = (wave >> 1) * 64;                 // 2x2 wave grid
    const int wcol = (wave & 1) * 64;
    const int lm   = lane & 15;
    const int quad = lane >> 4;
    const int l8r  = lane >> 3;                        // row-in-8 for staging
    const int swz  = ((lane & 7) ^ l8r) << 3;          // source chunk (elements)

    f32x4 acc[4][4];
    #pragma unroll
    for (int i = 0; i < 4; ++i)
        #pragma unroll
        for (int j = 0; j < 4; ++j)
            #pragma unroll
            for (int r = 0; r < 4; ++r) acc[i][j][r] = 0.0f;

    int aoff[2][4], boff[2][4];
    #pragma unroll
    for (int kc = 0; kc < 2; ++kc) {
        int g = kc*4 + quad;
        #pragma unroll
        for (int i = 0; i < 4; ++i) {
            int row = wrow + i*16 + lm;
            aoff[kc][i] = row*128 + ((g ^ (row & 7)) << 4);
        }
        #pragma unroll
        for (int j = 0; j < 4; ++j) {
            int d = wcol + j*16 + lm;
            boff[kc][j] = d*128 + ((g ^ (d & 7)) << 4);
        }
    }

    // ---- staging for tile 'it' into buffer 'buf' (B first: no idx dep) ----
    #define STAGE(buf, it)                                                     \
    {                                                                          \
        const int h_  = ((it) >= KOFF) ? 1 : 0;                                \
        const int kk_ = (it) - h_*KOFF;                                        \
        const u16* wb_ = Wt + (size_t)kk_*CH*CH + h_*64 + swz;                 \
        _Pragma("unroll")                                                      \
        for (int j_ = 0; j_ < 4; ++j_) {                                       \
            int row8_ = wave*32 + j_*8;                                        \
            GLDS16(wb_ + (size_t)(row8_ + l8r)*CH, &B_lds[buf][row8_*64]);     \
        }                                                                      \
        int nb4_[4];                                                           \
        _Pragma("unroll")                                                      \
        for (int j_ = 0; j_ < 4; ++j_)                                         \
            nb4_[j_] = idx_lds[(wave*32 + j_*8 + l8r)*KOFF + kk_];             \
        _Pragma("unroll")                                                      \
        for (int j_ = 0; j_ < 4; ++j_) {                                       \
            int row8_ = wave*32 + j_*8;                                        \
            GLDS16(xb + (size_t)nb4_[j_]*CH + h_*64 + swz,                     \
                   &A_lds[buf][row8_*64]);                                     \
        }                                                                      \
    }

    STAGE(0, 0);
    __syncthreads();                   // drain prologue staging

    int cur = 0;
    for (int it = 0; it < NITER; ++it) {
        if (it + 1 < NITER) STAGE(cur ^ 1, it + 1);   // prefetch overlaps MFMA

        const char* Ab = (const char*)A_lds[cur];
        const char* Bb = (const char*)B_lds[cur];
        #pragma unroll
        for (int kc = 0; kc < 2; ++kc) {
            short8 a[4], b[4];
            #pragma unroll
            for (int i = 0; i < 4; ++i) a[i] = *(const short8*)(Ab + aoff[kc][i]);
            #pragma unroll
            for (int j = 0; j < 4; ++j) b[j] = *(const short8*)(Bb + boff[kc][j]);
            #pragma unroll
            for (int i = 0; i < 4; ++i)
                #pragma unroll
                for (int j = 0; j < 4; ++j)
                    acc[i][j] = __builtin_amdgcn_mfma_f32_16x16x32_bf16(a[i], b[j], acc[i][j], 0, 0, 0);
        }
        __syncthreads();   // reads done (next STAGE overwrites cur^1's prior)
                           // + drains prefetch vmcnt -> buf cur^1 ready
        cur ^= 1;
    }
    #undef STAGE

    // epilogue: C/D layout col=lane&15, row=quad*4+reg. Full fp32 K-sum ->
    // y bf16 + exact per-channel sum/sumsq (LDS reduce, global atomics).
    float s[4], q[4];
    #pragma unroll
    for (int j = 0; j < 4; ++j) { s[j] = 0.0f; q[j] = 0.0f; }
    #pragma unroll
    for (int i = 0; i < 4; ++i) {
        #pragma unroll
        for (int r = 0; r < 4; ++r) {
            int row = n0 + wrow + i*16 + quad*4 + r;
            u16* pp = y + (size_t)row*CH + wcol + lm;
            #pragma unroll
            for (int j = 0; j < 4; ++j) {
                float v = acc[i][j][r];
                pp[j*16] = f2bf(v);
                s[j] += v; q[j] += v*v;
            }
        }
    }
    #pragma unroll
    for (int j = 0; j < 4; ++j) {
        atomicAdd(&ls[wcol + j*16 + lm], s[j]);
        atomicAdd(&lq[wcol + j*16 + lm], q[j]);
    }
    __syncthreads();
    if (tid < CH) {
        atomicAdd(&gsum[tid], ls[tid]);
        atomicAdd(&gsq[tid],  lq[tid]);
    }
}

// ---------------------------------------------------------------------------
// norm_relu: xo(bf16) = relu(bn(y; g,b)),  y bf16, 8 elems/thread
// ---------------------------------------------------------------------------
__global__ __launch_bounds__(256)
void norm_relu_kernel(const u16* __restrict__ y, const float* __restrict__ sums,
                      const float* __restrict__ sumsq, const float* __restrict__ gam,
                      const float* __restrict__ bet, u16* __restrict__ xo)
{
    __shared__ float sc[128], sh[128];
    const int tid = threadIdx.x;
    if (tid < 128) {
        float mu  = sums[tid] * (1.0f/NPTS);
        float var = fmaxf(sumsq[tid] * (1.0f/NPTS) - mu*mu, 0.0f);
        float rs  = rsqrtf(var + 1e-5f);
        float s   = rs * gam[tid];
        sc[tid] = s; sh[tid] = bet[tid] - mu*s;
    }
    __syncthreads();
    size_t e = ((size_t)blockIdx.x*256 + tid) * 8;
    int c0 = (int)(e & 127);
    ushort4 lo = *(const ushort4*)(y + e);
    ushort4 hi = *(const ushort4*)(y + e + 4);
    ushort4 o0, o1;
    o0.x = f2bf(fmaxf(bf2f(lo.x)*sc[c0+0] + sh[c0+0], 0.0f));
    o0.y = f2bf(fmaxf(bf2f(lo.y)*sc[c0+1] + sh[c0+1], 0.0f));
    o0.z = f2bf(fmaxf(bf2f(lo.z)*sc[c0+2] + sh[c0+2], 0.0f));
    o0.w = f2bf(fmaxf(bf2f(lo.w)*sc[c0+3] + sh[c0+3], 0.0f));
    o1.x = f2bf(fmaxf(bf2f(hi.x)*sc[c0+4] + sh[c0+4], 0.0f));
    o1.y = f2bf(fmaxf(bf2f(hi.y)*sc[c0+5] + sh[c0+5], 0.0f));
    o1.z = f2bf(fmaxf(bf2f(hi.z)*sc[c0+6] + sh[c0+6], 0.0f));
    o1.w = f2bf(fmaxf(bf2f(hi.w)*sc[c0+7] + sh[c0+7], 0.0f));
    *(ushort4*)(xo + e) = o0;
    *(ushort4*)(xo + e + 4) = o1;
}

// ---------------------------------------------------------------------------
// final: out(fp32) = relu(bn(y2; g,b) + feats)   (y2 bf16, feats/out fp32)
// ---------------------------------------------------------------------------
__global__ __launch_bounds__(256)
void final_kernel(const u16* __restrict__ y, const float* __restrict__ sums,
                  const float* __restrict__ sumsq, const float* __restrict__ gam,
                  const float* __restrict__ bet, const float* __restrict__ feats,
                  float* __restrict__ out)
{
    __shared__ float sc[128], sh[128];
    const int tid = threadIdx.x;
    if (tid < 128) {
        float mu  = sums[tid] * (1.0f/NPTS);
        float var = fmaxf(sumsq[tid] * (1.0f/NPTS) - mu*mu, 0.0f);
        float rs  = rsqrtf(var + 1e-5f);
        float s   = rs * gam[tid];
        sc[tid] = s; sh[tid] = bet[tid] - mu*s;
    }
    __syncthreads();
    size_t e = ((size_t)blockIdx.x*256 + tid) * 4;
    int c0 = (int)(e & 127);
    ushort4 in = *(const ushort4*)(y + e);
    float4 ft = *(const float4*)(feats + e);
    float4 o;
    o.x = fmaxf(bf2f(in.x)*sc[c0+0] + sh[c0+0] + ft.x, 0.0f);
    o.y = fmaxf(bf2f(in.y)*sc[c0+1] + sh[c0+1] + ft.y, 0.0f);
    o.z = fmaxf(bf2f(in.z)*sc[c0+2] + sh[c0+2] + ft.z, 0.0f);
    o.w = fmaxf(bf2f(in.w)*sc[c0+3] + sh[c0+3] + ft.w, 0.0f);
    *(float4*)(out + e) = o;
}

// ---------------------------------------------------------------------------
extern "C" void kernel_launch(void* const* d_in, const int* in_sizes, int n_in,
                              void* d_out, int out_size, void* d_ws, size_t ws_size,
                              hipStream_t stream)
{
    const float* feats = (const float*)d_in[0];
    const int*   nbr   = (const int*)d_in[1];
    const float* W1    = (const float*)d_in[2];
    const float* g1    = (const float*)d_in[3];
    const float* b1    = (const float*)d_in[4];
    const float* W2    = (const float*)d_in[5];
    const float* g2    = (const float*)d_in[6];
    const float* b2    = (const float*)d_in[7];
    float* out = (float*)d_out;

    // ws (~18.6 MB): xbuf | ybuf (bf16) | Wt1 | Wt2 | stat[512]
    char* ws = (char*)d_ws;
    u16*   xbuf = (u16*)ws;                                   // 8.4 MB
    u16*   ybuf = xbuf + (size_t)NC;                          // 8.4 MB
    u16*   W1t  = ybuf + (size_t)NC;
    u16*   W2t  = W1t + (size_t)KOFF*CH*CH;
    float* stat = (float*)(W2t + (size_t)KOFF*CH*CH);         // s1,q1,s2,q2

    prep_kernel<<<dim3(2*KOFF + NC/2048), 256, 0, stream>>>(W1, W2, W1t, W2t, feats, xbuf, stat);

    ResidualBlock_77498389889548_kernel<<<dim3(NPTS/TILE_M), 256, 0, stream>>>(
        xbuf, nbr, W1t, ybuf, stat, stat + 128);
    norm_relu_kernel<<<dim3(NC/2048), 256, 0, stream>>>(ybuf, stat, stat + 128, g1, b1, xbuf);

    ResidualBlock_77498389889548_kernel<<<dim3(NPTS/TILE_M), 256, 0, stream>>>(
        xbuf, nbr, W2t, ybuf, stat + 256, stat + 384);
    final_kernel<<<dim3(NC/1024), 256, 0, stream>>>(ybuf, stat + 256, stat + 384, g2, b2, feats, out);
}